// Round 3
// baseline (282.081 us; speedup 1.0000x reference)
//
#include <hip/hip_runtime.h>
#include <cstdint>

#define N_VIS   8192
#define N_ASSOC 4096
#define N_MOTOR 1024
#define IN_DIM  4096
#define T_STEPS 16

// ---------------- encoder + visual LIF: 4 rows per wave, 16 rows per block ----------------
// Body is bit-identical to the passing round-2 version; launch_bounds(256,2) lets the
// 64 accumulators live in arch VGPRs instead of bouncing through AGPRs.
__global__ __launch_bounds__(256, 2) void encoder_kernel(
        const float* __restrict__ x, const float* __restrict__ noise,
        const float* __restrict__ W, const float* __restrict__ b,
        unsigned* __restrict__ vmask) {
    const int wave = threadIdx.x >> 6, lane = threadIdx.x & 63;
    const int i0 = (blockIdx.x * 4 + wave) * 4;      // first of this wave's 4 rows
    const float4* r0 = (const float4*)(W + (size_t)(i0 + 0) * IN_DIM);
    const float4* r1 = (const float4*)(W + (size_t)(i0 + 1) * IN_DIM);
    const float4* r2 = (const float4*)(W + (size_t)(i0 + 2) * IN_DIM);
    const float4* r3 = (const float4*)(W + (size_t)(i0 + 3) * IN_DIM);

    float acc0[T_STEPS], acc1[T_STEPS], acc2[T_STEPS], acc3[T_STEPS];
#pragma unroll
    for (int t = 0; t < T_STEPS; ++t) { acc0[t]=0.f; acc1[t]=0.f; acc2[t]=0.f; acc3[t]=0.f; }

    for (int m = 0; m < 16; ++m) {
        const int k4 = m * 64 + lane;                // float4 index within row
        float4 w0 = r0[k4], w1 = r1[k4], w2 = r2[k4], w3 = r3[k4];
#pragma unroll
        for (int t = 0; t < T_STEPS; ++t) {
            float4 xv = ((const float4*)(x + t * IN_DIM))[k4];
            acc0[t] += w0.x*xv.x + w0.y*xv.y + w0.z*xv.z + w0.w*xv.w;
            acc1[t] += w1.x*xv.x + w1.y*xv.y + w1.z*xv.z + w1.w*xv.w;
            acc2[t] += w2.x*xv.x + w2.y*xv.y + w2.z*xv.z + w2.w*xv.w;
            acc3[t] += w3.x*xv.x + w3.y*xv.y + w3.z*xv.z + w3.w*xv.w;
        }
    }
#pragma unroll
    for (int t = 0; t < T_STEPS; ++t) {
        float a;
        a = acc0[t]; for (int off = 32; off; off >>= 1) a += __shfl_xor(a, off, 64); acc0[t] = a;
        a = acc1[t]; for (int off = 32; off; off >>= 1) a += __shfl_xor(a, off, 64); acc1[t] = a;
        a = acc2[t]; for (int off = 32; off; off >>= 1) a += __shfl_xor(a, off, 64); acc2[t] = a;
        a = acc3[t]; for (int off = 32; off; off >>= 1) a += __shfl_xor(a, off, 64); acc3[t] = a;
    }
    if (lane == 0) {
        auto do_row = [&](int i, const float (&a)[T_STEPS]) {
            float bb = b[i];
            float v = 0.f;
            unsigned msk = 0;
#pragma unroll
            for (int t = 0; t < T_STEPS; ++t) {
                float logit = a[t] + bb;
                float rate = 1.0f / (1.0f + expf(-logit));
                float u = noise[t * N_VIS + i];
                float ins = (u < rate * 0.3f) ? 1.0f : 0.0f;
                v = v * 0.95f + ins;
                if (v > 1.0f) { msk |= (1u << t); v = 0.f; }
            }
            vmask[i] = msk;
        };
        do_row(i0 + 0, acc0);
        do_row(i0 + 1, acc1);
        do_row(i0 + 2, acc2);
        do_row(i0 + 3, acc3);
    }
}

// ---------------- one block (512 thr) per row: all 16 steps in registers ----------------
// F = float4 chunks per thread (row length / 2048).
template<int F>
__global__ __launch_bounds__(512) void snn_layer_kernel(
        const float* __restrict__ W0, const unsigned* __restrict__ colmask,
        const float* __restrict__ dop, unsigned* __restrict__ rowmask_out,
        float* __restrict__ outp, int out_stride) {
    const int j = blockIdx.x;
    const int tid = threadIdx.x;
    const int lane = tid & 63, wv_id = tid >> 6;     // 8 waves
    __shared__ float sred[2][8];
    __shared__ float sdop[T_STEPS];

    if (tid < T_STEPS) sdop[tid] = dop[tid];

    const float4* Wr = (const float4*)(W0 + (size_t)j * (F * 2048));
    const uint4*  cm = (const uint4*)colmask;

    float    w[F * 4];
    float    e[F * 4];
    unsigned vmp[F * 2];          // packed: low 16 bits = comp {x,z}, high 16 = comp {y,w}
#pragma unroll
    for (int k = 0; k < F; ++k) {
        float4 wv4 = Wr[tid + k * 512];
        uint4  mv  = cm[tid + k * 512];
        w[k*4+0] = wv4.x; w[k*4+1] = wv4.y; w[k*4+2] = wv4.z; w[k*4+3] = wv4.w;
        vmp[k*2+0] = mv.x | (mv.y << 16);
        vmp[k*2+1] = mv.z | (mv.w << 16);
        e[k*4+0] = 0.f; e[k*4+1] = 0.f; e[k*4+2] = 0.f; e[k*4+3] = 0.f;
    }
    __syncthreads();

    float    decay_next = 0.998f;      // folds the bit-exact x0.5 halving of gated steps
    float    vmem = 0.f;               // maintained redundantly by every thread
    unsigned rmask = 0;

#pragma unroll 1
    for (int t = 0; t < T_STEPS; ++t) {
        // ---- matvec with current W against column-spikes of step t ----
        float acc = 0.f;
#pragma unroll
        for (int k = 0; k < F; ++k) {
            acc = fmaf(w[k*4+0], (float)((vmp[k*2+0] >> t)        & 1u), acc);
            acc = fmaf(w[k*4+1], (float)((vmp[k*2+0] >> (t + 16)) & 1u), acc);
            acc = fmaf(w[k*4+2], (float)((vmp[k*2+1] >> t)        & 1u), acc);
            acc = fmaf(w[k*4+3], (float)((vmp[k*2+1] >> (t + 16)) & 1u), acc);
        }
        for (int off = 32; off; off >>= 1) acc += __shfl_down(acc, off, 64);
        if (lane == 0) sred[t & 1][wv_id] = acc;
        __syncthreads();

        // ---- LIF, computed redundantly (deterministic, identical on all threads) ----
        const float* sr = sred[t & 1];
        float tot = sr[0]; tot += sr[1]; tot += sr[2]; tot += sr[3];
        tot += sr[4]; tot += sr[5]; tot += sr[6]; tot += sr[7];
        vmem = vmem * 0.95f + tot * 0.1f;
        const bool spike = vmem > 1.0f;
        if (spike) { vmem = 0.f; rmask |= (1u << t); }
        if (outp && tid == 0) outp[t * out_stride + j] = spike ? 1.0f : 0.0f;

        // ---- eligibility + gated plastic update (dead at t=15) ----
        if (t != T_STEPS - 1) {
            const float d  = sdop[t];
            const bool  g  = fabsf(d) > 0.1f;
            const float dm = decay_next;
            if (spike) {                               // uniform branch
#pragma unroll
                for (int k = 0; k < F; ++k) {
                    e[k*4+0] = fmaf(e[k*4+0], dm, (float)((vmp[k*2+0] >> t)        & 1u) * 0.01f);
                    e[k*4+1] = fmaf(e[k*4+1], dm, (float)((vmp[k*2+0] >> (t + 16)) & 1u) * 0.01f);
                    e[k*4+2] = fmaf(e[k*4+2], dm, (float)((vmp[k*2+1] >> t)        & 1u) * 0.01f);
                    e[k*4+3] = fmaf(e[k*4+3], dm, (float)((vmp[k*2+1] >> (t + 16)) & 1u) * 0.01f);
                }
            } else {
#pragma unroll
                for (int el = 0; el < F * 4; ++el) e[el] = e[el] * dm;
            }
            if (g) {                                   // uniform branch
#pragma unroll
                for (int el = 0; el < F * 4; ++el) {
                    float delta = (d * e[el]) * 0.1f;          // ref op order
                    delta = fminf(fmaxf(delta, -0.01f), 0.01f);
                    w[el] = fmaxf(w[el] + delta, 0.0f);        // upper clip provably dead (w<=0.2)
                }
            }
            decay_next = g ? (0.998f * 0.5f) : 0.998f;
        }
    }
    if (tid == 0 && rowmask_out) rowmask_out[j] = rmask;
}

extern "C" void kernel_launch(void* const* d_in, const int* in_sizes, int n_in,
                              void* d_out, int out_size, void* d_ws, size_t ws_size,
                              hipStream_t stream) {
    const float* x     = (const float*)d_in[0];   // [16, 4096]
    const float* noise = (const float*)d_in[1];   // [16, 8192]
    const float* dop   = (const float*)d_in[2];   // [16]
    const float* W_enc = (const float*)d_in[3];   // [8192, 4096]
    const float* b_enc = (const float*)d_in[4];   // [8192]
    const float* W_va  = (const float*)d_in[5];   // [4096, 8192]
    const float* W_am  = (const float*)d_in[6];   // [1024, 4096]
    float* out = (float*)d_out;                   // [16, 1024] f32
    (void)in_sizes; (void)n_in; (void)out_size; (void)ws_size;

    unsigned* vmask = (unsigned*)d_ws;            // [8192]
    unsigned* amask = vmask + N_VIS;              // [4096]

    encoder_kernel<<<N_VIS / 16, 256, 0, stream>>>(x, noise, W_enc, b_enc, vmask);
    snn_layer_kernel<4><<<N_ASSOC, 512, 0, stream>>>(W_va, vmask, dop, amask, nullptr, 0);
    snn_layer_kernel<2><<<N_MOTOR, 512, 0, stream>>>(W_am, amask, dop, nullptr, out, N_MOTOR);
}

// Round 4
// 228.626 us; speedup vs baseline: 1.2338x; 1.2338x over previous
//
#include <hip/hip_runtime.h>
#include <cstdint>

#define N_VIS   8192
#define N_ASSOC 4096
#define N_MOTOR 1024
#define IN_DIM  4096
#define T_STEPS 16

// ---------------- encoder + visual LIF: x staged in LDS, 2 rows/wave, 8 rows/block ----------------
__global__ __launch_bounds__(256, 4) void encoder_kernel(
        const float* __restrict__ x, const float* __restrict__ noise,
        const float* __restrict__ W, const float* __restrict__ b,
        unsigned* __restrict__ vmask) {
    __shared__ float4 xs[16 * 64];               // [t][64 float4] tile of one 256-col chunk (16 KB)
    const int tid = threadIdx.x;
    const int wave = tid >> 6, lane = tid & 63;
    const int r0 = blockIdx.x * 8 + wave * 2;    // this wave's two rows
    const float4* W0 = (const float4*)(W + (size_t)r0 * IN_DIM);
    const float4* W1 = (const float4*)(W + (size_t)(r0 + 1) * IN_DIM);

    float a0[T_STEPS], a1[T_STEPS];
#pragma unroll
    for (int t = 0; t < T_STEPS; ++t) { a0[t] = 0.f; a1[t] = 0.f; }

    for (int c = 0; c < 16; ++c) {
        __syncthreads();
#pragma unroll
        for (int p = 0; p < 4; ++p) {
            int f = tid + p * 256;               // flat index over [16 t][64 c4]
            int t = f >> 6, c4 = f & 63;
            xs[f] = ((const float4*)(x + (size_t)t * IN_DIM + c * 256))[c4];
        }
        __syncthreads();
        float4 w0 = W0[c * 64 + lane];
        float4 w1 = W1[c * 64 + lane];
#pragma unroll
        for (int t = 0; t < T_STEPS; ++t) {
            float4 xv = xs[t * 64 + lane];
            a0[t] += w0.x*xv.x + w0.y*xv.y + w0.z*xv.z + w0.w*xv.w;
            a1[t] += w1.x*xv.x + w1.y*xv.y + w1.z*xv.z + w1.w*xv.w;
        }
    }
#pragma unroll
    for (int t = 0; t < T_STEPS; ++t) {
        float v;
        v = a0[t]; for (int o = 32; o; o >>= 1) v += __shfl_xor(v, o, 64); a0[t] = v;
        v = a1[t]; for (int o = 32; o; o >>= 1) v += __shfl_xor(v, o, 64); a1[t] = v;
    }
    if (lane == 0) {
        auto do_row = [&](int i, const float (&a)[T_STEPS]) {
            float bb = b[i];
            float v = 0.f;
            unsigned msk = 0;
#pragma unroll
            for (int t = 0; t < T_STEPS; ++t) {
                float logit = a[t] + bb;
                float rate = 1.0f / (1.0f + expf(-logit));
                float u = noise[t * N_VIS + i];
                float ins = (u < rate * 0.3f) ? 1.0f : 0.0f;
                v = v * 0.95f + ins;
                if (v > 1.0f) { msk |= (1u << t); v = 0.f; }
            }
            vmask[i] = msk;
        };
        do_row(r0, a0);
        do_row(r0 + 1, a1);
    }
}

// ---------------- snn layer: 2 rows per 512-thread block, all 16 steps in registers ----------------
// NF = float4 chunks per thread per row (row length L = NF*2048).
template<int NF>
__global__ __launch_bounds__(512, 4) void snn_layer_kernel(
        const float* __restrict__ Wg, const unsigned* __restrict__ colmask,
        const float* __restrict__ dop, unsigned* __restrict__ rowmask_out,
        float* __restrict__ outp, int out_stride) {
    const int j0 = blockIdx.x * 2;
    const int tid = threadIdx.x;
    const int lane = tid & 63, wv = tid >> 6;        // 8 waves
    __shared__ float sred[2][2][8];                  // [pingpong][row][wave]
    __shared__ float sdop[T_STEPS];
    if (tid < T_STEPS) sdop[tid] = dop[tid];

    const int L = NF * 2048;
    const float4* Wr0 = (const float4*)(Wg + (size_t)j0 * L);
    const float4* Wr1 = (const float4*)(Wg + (size_t)(j0 + 1) * L);
    const uint4*  cm  = (const uint4*)colmask;

    float w0[NF*4], w1[NF*4], e0[NF*4], e1[NF*4], bf[NF*4];
    unsigned vmp[NF*2];                              // packed: low16 = {x,z}, high16 = {y,w}
#pragma unroll
    for (int k = 0; k < NF; ++k) {
        float4 q0 = Wr0[tid + k*512];
        float4 q1 = Wr1[tid + k*512];
        uint4  mv = cm [tid + k*512];
        w0[k*4+0]=q0.x; w0[k*4+1]=q0.y; w0[k*4+2]=q0.z; w0[k*4+3]=q0.w;
        w1[k*4+0]=q1.x; w1[k*4+1]=q1.y; w1[k*4+2]=q1.z; w1[k*4+3]=q1.w;
        vmp[k*2+0] = mv.x | (mv.y << 16);
        vmp[k*2+1] = mv.z | (mv.w << 16);
        e0[k*4+0]=0.f; e0[k*4+1]=0.f; e0[k*4+2]=0.f; e0[k*4+3]=0.f;
        e1[k*4+0]=0.f; e1[k*4+1]=0.f; e1[k*4+2]=0.f; e1[k*4+3]=0.f;
    }
    __syncthreads();                                 // covers sdop too

    float decay_next = 0.998f;
    float v0 = 0.f, v1 = 0.f;
    unsigned rm0 = 0, rm1 = 0;
    bool st0 = false, st1 = false;                   // row has spiked at least once

#pragma unroll 1
    for (int t = 0; t < T_STEPS; ++t) {
        // ---- matvec for both rows; bit->float shared, kept in bf[] for the update phase ----
        float acc0 = 0.f, acc1 = 0.f;
#pragma unroll
        for (int k = 0; k < NF; ++k) {
            float bx = (float)((vmp[k*2+0] >> t)        & 1u);
            float by = (float)((vmp[k*2+0] >> (t + 16)) & 1u);
            float bz = (float)((vmp[k*2+1] >> t)        & 1u);
            float bw = (float)((vmp[k*2+1] >> (t + 16)) & 1u);
            bf[k*4+0]=bx; bf[k*4+1]=by; bf[k*4+2]=bz; bf[k*4+3]=bw;
            acc0 = fmaf(w0[k*4+0], bx, acc0); acc0 = fmaf(w0[k*4+1], by, acc0);
            acc0 = fmaf(w0[k*4+2], bz, acc0); acc0 = fmaf(w0[k*4+3], bw, acc0);
            acc1 = fmaf(w1[k*4+0], bx, acc1); acc1 = fmaf(w1[k*4+1], by, acc1);
            acc1 = fmaf(w1[k*4+2], bz, acc1); acc1 = fmaf(w1[k*4+3], bw, acc1);
        }
        for (int o = 32; o; o >>= 1) {
            acc0 += __shfl_down(acc0, o, 64);
            acc1 += __shfl_down(acc1, o, 64);
        }
        if (lane == 0) { sred[t&1][0][wv] = acc0; sred[t&1][1][wv] = acc1; }
        __syncthreads();

        // ---- LIF, redundantly on all threads (identical FP ops -> identical results) ----
        const float* s0p = sred[t&1][0];
        const float* s1p = sred[t&1][1];
        float tot0 = s0p[0]; tot0 += s0p[1]; tot0 += s0p[2]; tot0 += s0p[3];
        tot0 += s0p[4]; tot0 += s0p[5]; tot0 += s0p[6]; tot0 += s0p[7];
        float tot1 = s1p[0]; tot1 += s1p[1]; tot1 += s1p[2]; tot1 += s1p[3];
        tot1 += s1p[4]; tot1 += s1p[5]; tot1 += s1p[6]; tot1 += s1p[7];
        v0 = v0 * 0.95f + tot0 * 0.1f;
        v1 = v1 * 0.95f + tot1 * 0.1f;
        const bool s0 = v0 > 1.0f; if (s0) { v0 = 0.f; rm0 |= (1u << t); }
        const bool s1 = v1 > 1.0f; if (s1) { v1 = 0.f; rm1 |= (1u << t); }
        if (outp && tid == 0) {
            outp[t * out_stride + j0]     = s0 ? 1.0f : 0.0f;
            outp[t * out_stride + j0 + 1] = s1 ? 1.0f : 0.0f;
        }

        // ---- eligibility + gated plastic update (dead at t=15; dead per-row until first spike) ----
        if (t != T_STEPS - 1) {
            const float d  = sdop[t];
            const bool  g  = fabsf(d) > 0.1f;
            const float dm = decay_next;
            st0 |= s0; st1 |= s1;
            const float inc0 = s0 ? 0.01f : 0.0f;
            const float inc1 = s1 ? 0.01f : 0.0f;
            if (st0) {
                if (g) {
#pragma unroll
                    for (int el = 0; el < NF*4; ++el) {
                        e0[el] = fmaf(e0[el], dm, bf[el] * inc0);
                        float dl = (d * e0[el]) * 0.1f;               // ref op order
                        dl = fminf(fmaxf(dl, -0.01f), 0.01f);
                        w0[el] = fmaxf(w0[el] + dl, 0.0f);            // upper clip dead (w<=0.2)
                    }
                } else {
#pragma unroll
                    for (int el = 0; el < NF*4; ++el)
                        e0[el] = fmaf(e0[el], dm, bf[el] * inc0);
                }
            }
            if (st1) {
                if (g) {
#pragma unroll
                    for (int el = 0; el < NF*4; ++el) {
                        e1[el] = fmaf(e1[el], dm, bf[el] * inc1);
                        float dl = (d * e1[el]) * 0.1f;
                        dl = fminf(fmaxf(dl, -0.01f), 0.01f);
                        w1[el] = fmaxf(w1[el] + dl, 0.0f);
                    }
                } else {
#pragma unroll
                    for (int el = 0; el < NF*4; ++el)
                        e1[el] = fmaf(e1[el], dm, bf[el] * inc1);
                }
            }
            decay_next = g ? (0.998f * 0.5f) : 0.998f;                // bit-exact fold
        }
    }
    if (tid == 0 && rowmask_out) { rowmask_out[j0] = rm0; rowmask_out[j0 + 1] = rm1; }
}

extern "C" void kernel_launch(void* const* d_in, const int* in_sizes, int n_in,
                              void* d_out, int out_size, void* d_ws, size_t ws_size,
                              hipStream_t stream) {
    const float* x     = (const float*)d_in[0];   // [16, 4096]
    const float* noise = (const float*)d_in[1];   // [16, 8192]
    const float* dop   = (const float*)d_in[2];   // [16]
    const float* W_enc = (const float*)d_in[3];   // [8192, 4096]
    const float* b_enc = (const float*)d_in[4];   // [8192]
    const float* W_va  = (const float*)d_in[5];   // [4096, 8192]
    const float* W_am  = (const float*)d_in[6];   // [1024, 4096]
    float* out = (float*)d_out;                   // [16, 1024] f32
    (void)in_sizes; (void)n_in; (void)out_size; (void)ws_size;

    unsigned* vmask = (unsigned*)d_ws;            // [8192]
    unsigned* amask = vmask + N_VIS;              // [4096]

    encoder_kernel<<<N_VIS / 8, 256, 0, stream>>>(x, noise, W_enc, b_enc, vmask);
    snn_layer_kernel<4><<<N_ASSOC / 2, 512, 0, stream>>>(W_va, vmask, dop, amask, nullptr, 0);
    snn_layer_kernel<2><<<N_MOTOR / 2, 512, 0, stream>>>(W_am, amask, dop, nullptr, out, N_MOTOR);
}